// Round 1
// baseline (402.557 us; speedup 1.0000x reference)
//
#include <hip/hip_runtime.h>
#include <hip/hip_bf16.h>
#include <stdint.h>

typedef unsigned short u16;
typedef u16 u16x4 __attribute__((ext_vector_type(4)));
typedef short bf16x8 __attribute__((ext_vector_type(8)));
typedef float f32x4 __attribute__((ext_vector_type(4)));

__device__ __forceinline__ u16 f2bf(float f) {
  union { float f; uint32_t u; } v; v.f = f;
  uint32_t u = v.u;
  // round-to-nearest-even bf16 (inputs are finite, no NaN handling needed)
  return (u16)((u + 0x7fffu + ((u >> 16) & 1u)) >> 16);
}

// ---------------- x fp32 -> bf16 ----------------
__global__ __launch_bounds__(256) void cvt_x_kernel(const float4* __restrict__ in,
                                                    u16x4* __restrict__ out, int n4) {
  int i = blockIdx.x * 256 + threadIdx.x;
  const int stride = gridDim.x * 256;
  for (; i < n4; i += stride) {
    float4 v = in[i];
    u16x4 o;
    o.x = f2bf(v.x); o.y = f2bf(v.y); o.z = f2bf(v.z); o.w = f2bf(v.w);
    out[i] = o;
  }
}

// ---------------- W_eff = W + 2*(loraB @ loraA), cast bf16 ----------------
// one block per output row n; R hard-assumed 16 (checked host-side)
__global__ __launch_bounds__(256) void weff_kernel(const float* __restrict__ W,
                                                   const float* __restrict__ A,   // [16][DIN]
                                                   const float* __restrict__ Bl,  // [DOUT][16]
                                                   u16* __restrict__ Wout, int DIN) {
  const int n = blockIdx.x;
  float bv[16];
#pragma unroll
  for (int r = 0; r < 16; ++r) bv[r] = 2.0f * Bl[n * 16 + r];
  const int iters = DIN / (256 * 4);
  for (int c = 0; c < iters; ++c) {
    const int k = (c * 256 + (int)threadIdx.x) * 4;
    float4 wv = *(const float4*)&W[(size_t)n * DIN + k];
#pragma unroll
    for (int r = 0; r < 16; ++r) {
      const float4 av = *(const float4*)&A[(size_t)r * DIN + k];
      wv.x += bv[r] * av.x;
      wv.y += bv[r] * av.y;
      wv.z += bv[r] * av.z;
      wv.w += bv[r] * av.w;
    }
    u16x4 o;
    o.x = f2bf(wv.x); o.y = f2bf(wv.y); o.z = f2bf(wv.z); o.w = f2bf(wv.w);
    *(u16x4*)&Wout[(size_t)n * DIN + k] = o;
  }
}

// ---------------- bf16 GEMM: C[M][N] = X[M][K] @ Weff[N][K]^T + bias ----------------
// m97 structure: 128x128 tile, BK=32, 4 waves (2x2), 16x16x32 MFMA,
// global_load_lds width=16 double-buffered staging, 1 barrier per K-step.
#define BM 128
#define BN 128
#define BK 32

__global__ __launch_bounds__(256, 2) void gemm_kernel(const u16* __restrict__ A,   // X bf16 [M][K]
                                                      const u16* __restrict__ B,   // Weff bf16 [N][K]
                                                      const float* __restrict__ bias,
                                                      float* __restrict__ C,
                                                      int M, int N, int K) {
  __shared__ u16 Ab[2][BM * BK];
  __shared__ u16 Bb[2][BM * BK];

  const int tid  = threadIdx.x;
  const int lane = tid & 63;
  const int wid  = tid >> 6;
  const int bm = blockIdx.y * BM;
  const int bn = blockIdx.x * BN;
  const int wm = (wid >> 1) * 64;   // wave row offset within tile
  const int wn = (wid & 1) * 64;    // wave col offset within tile
  const int lr = lane & 15;         // frag row/col
  const int lk = lane >> 4;         // frag k-group (k = lk*8 + i)

  // staging: thread tid covers LDS bytes [tid*16, tid*16+16) per call
  // -> row = c*64 + tid/4, k-offset = (tid&3)*8
  const int srow  = tid >> 2;
  const int skoff = (tid & 3) << 3;
  const u16* gA = A + (size_t)bm * K + skoff;
  const u16* gB = B + (size_t)bn * K + skoff;

  auto stage = [&](int buf, int t) {
    const int k0 = t * BK;
#pragma unroll
    for (int c = 0; c < 2; ++c) {
      const int row = c * 64 + srow;
      const u16* sa = gA + (size_t)row * K + k0;
      const u16* sb = gB + (size_t)row * K + k0;
      // dest must be wave-uniform; HW adds lane*16 bytes
      u16* da = &Ab[buf][c * 2048 + wid * 512];
      u16* db = &Bb[buf][c * 2048 + wid * 512];
      __builtin_amdgcn_global_load_lds((__attribute__((address_space(1))) const void*)sa,
                                       (__attribute__((address_space(3))) void*)da, 16, 0, 0);
      __builtin_amdgcn_global_load_lds((__attribute__((address_space(1))) const void*)sb,
                                       (__attribute__((address_space(3))) void*)db, 16, 0, 0);
    }
  };

  f32x4 acc[4][4];
#pragma unroll
  for (int i = 0; i < 4; ++i)
#pragma unroll
    for (int j = 0; j < 4; ++j) acc[i][j] = f32x4{0.f, 0.f, 0.f, 0.f};

  const int nt = K / BK;
  stage(0, 0);
  __syncthreads();

  int cur = 0;
  for (int t = 0; t < nt; ++t) {
    if (t + 1 < nt) stage(cur ^ 1, t + 1);

    bf16x8 af[4], bf[4];
#pragma unroll
    for (int mf = 0; mf < 4; ++mf)
      af[mf] = *(const bf16x8*)&Ab[cur][(wm + mf * 16 + lr) * BK + lk * 8];
#pragma unroll
    for (int nf = 0; nf < 4; ++nf)
      bf[nf] = *(const bf16x8*)&Bb[cur][(wn + nf * 16 + lr) * BK + lk * 8];

#pragma unroll
    for (int mf = 0; mf < 4; ++mf)
#pragma unroll
      for (int nf = 0; nf < 4; ++nf)
        acc[mf][nf] = __builtin_amdgcn_mfma_f32_16x16x32_bf16(af[mf], bf[nf], acc[mf][nf], 0, 0, 0);

    __syncthreads();   // drains vmcnt (next tile staged) + lgkmcnt (reads done)
    cur ^= 1;
  }

  // epilogue: C/D layout col = lane&15, row = (lane>>4)*4 + j  [m89-verified]
#pragma unroll
  for (int nf = 0; nf < 4; ++nf) {
    const int col = bn + wn + nf * 16 + lr;
    const float bv = bias[col];
#pragma unroll
    for (int mf = 0; mf < 4; ++mf) {
      const int row = bm + wm + mf * 16 + lk * 4;
#pragma unroll
      for (int j = 0; j < 4; ++j)
        C[(size_t)(row + j) * N + col] = acc[mf][nf][j] + bv;
    }
  }
}

extern "C" void kernel_launch(void* const* d_in, const int* in_sizes, int n_in,
                              void* d_out, int out_size, void* d_ws, size_t ws_size,
                              hipStream_t stream) {
  const float* x  = (const float*)d_in[0];   // [B,S,DIN] = [M][K]
  const float* w  = (const float*)d_in[1];   // [DOUT][DIN]
  const float* lA = (const float*)d_in[2];   // [R][DIN]
  const float* lB = (const float*)d_in[3];   // [DOUT][R]
  const float* bs = (const float*)d_in[4];   // [DOUT]
  float* out = (float*)d_out;

  const int DOUT = in_sizes[4];              // 4096
  const int DIN  = in_sizes[1] / DOUT;       // 4096
  const int M    = in_sizes[0] / DIN;        // 8192

  u16* Xb = (u16*)d_ws;                      // M*DIN bf16  (64 MB)
  u16* Wb = Xb + (size_t)M * DIN;            // DOUT*DIN bf16 (32 MB)

  const int n4 = (M * DIN) / 4;
  cvt_x_kernel<<<2048, 256, 0, stream>>>((const float4*)x, (u16x4*)Xb, n4);
  weff_kernel<<<DOUT, 256, 0, stream>>>(w, lA, lB, Wb, DIN);

  dim3 grid(DOUT / BN, M / BM);
  gemm_kernel<<<grid, 256, 0, stream>>>(Xb, Wb, bs, out, M, DOUT, DIN);
}

// Round 2
// 342.315 us; speedup vs baseline: 1.1760x; 1.1760x over previous
//
#include <hip/hip_runtime.h>
#include <hip/hip_bf16.h>
#include <stdint.h>

typedef unsigned short u16;
typedef u16 u16x4 __attribute__((ext_vector_type(4)));
typedef short bf16x8 __attribute__((ext_vector_type(8)));
typedef float f32x4 __attribute__((ext_vector_type(4)));

__device__ __forceinline__ u16 f2bf(float f) {
  union { float f; uint32_t u; } v; v.f = f;
  uint32_t u = v.u;
  return (u16)((u + 0x7fffu + ((u >> 16) & 1u)) >> 16);
}

// ---------------- x fp32 -> bf16 ----------------
__global__ __launch_bounds__(256) void cvt_x_kernel(const float4* __restrict__ in,
                                                    u16x4* __restrict__ out, int n4) {
  int i = blockIdx.x * 256 + threadIdx.x;
  const int stride = gridDim.x * 256;
  for (; i < n4; i += stride) {
    float4 v = in[i];
    u16x4 o;
    o.x = f2bf(v.x); o.y = f2bf(v.y); o.z = f2bf(v.z); o.w = f2bf(v.w);
    out[i] = o;
  }
}

// ---------------- W_eff = W + 2*(loraB @ loraA), cast bf16 ----------------
__global__ __launch_bounds__(256) void weff_kernel(const float* __restrict__ W,
                                                   const float* __restrict__ A,   // [16][DIN]
                                                   const float* __restrict__ Bl,  // [DOUT][16]
                                                   u16* __restrict__ Wout, int DIN) {
  const int n = blockIdx.x;
  float bv[16];
#pragma unroll
  for (int r = 0; r < 16; ++r) bv[r] = 2.0f * Bl[n * 16 + r];
  const int iters = DIN / (256 * 4);
  for (int c = 0; c < iters; ++c) {
    const int k = (c * 256 + (int)threadIdx.x) * 4;
    float4 wv = *(const float4*)&W[(size_t)n * DIN + k];
#pragma unroll
    for (int r = 0; r < 16; ++r) {
      const float4 av = *(const float4*)&A[(size_t)r * DIN + k];
      wv.x += bv[r] * av.x;
      wv.y += bv[r] * av.y;
      wv.z += bv[r] * av.z;
      wv.w += bv[r] * av.w;
    }
    u16x4 o;
    o.x = f2bf(wv.x); o.y = f2bf(wv.y); o.z = f2bf(wv.z); o.w = f2bf(wv.w);
    *(u16x4*)&Wout[(size_t)n * DIN + k] = o;
  }
}

// ---------------- 256x256 deep-pipelined bf16 GEMM ----------------
// C[M][N] = X[M][K] @ Weff[N][K]^T + bias
// K-chunk = 64 = 2 ksubs of 32. LDS slab = 256 rows x 32 k bf16 = 16 KB.
// A slabs: [par][ks] at (par*2+ks)*8192 u16; B slabs at +32768 u16. Total 128 KiB.
// Per chunk: 4 phases; gates (vmcnt(4) + barrier) at phases 0 and 2 only.
// Staging of chunk t+1's 4 slabs is spread 1-per-phase across chunk t.
#define BM 256
#define BN 256

__global__ __launch_bounds__(512, 2) void gemm256_kernel(
    const u16* __restrict__ A, const u16* __restrict__ B,
    const float* __restrict__ bias, float* __restrict__ C,
    int M, int N, int K) {
  extern __shared__ u16 lds[];   // 131072 bytes

  const int tid  = threadIdx.x;
  const int lane = tid & 63;
  const int wid  = tid >> 6;

  // XCD-aware block swizzle (nwg % 8 == 0 guaranteed by launch)
  const int nwg = gridDim.x;
  const int cpx = nwg >> 3;
  const int f   = ((int)blockIdx.x & 7) * cpx + ((int)blockIdx.x >> 3);
  const int nbx = N / BN;
  const int bx = f % nbx, by = f / nbx;
  const int bm = by * BM, bn = bx * BN;

  const int wmL = (wid >> 2) * 128;   // 2 M-wave rows
  const int wnL = (wid & 3) * 64;     // 4 N-wave cols
  const int lr  = lane & 15;
  const int lk  = lane >> 4;
  // swizzled ds_read k-slot (lane-constant): slot' = lk ^ ((row>>1)&3), row≡lr mod 16
  const int rslot = ((lk ^ ((lr >> 1) & 3)) << 3);  // u16 offset within 32-elem row

  // staging source mapping (pre-swizzled global source, linear LDS dest):
  // LDS linear: row = tid>>2 (+128*issue), slot q = tid&3 ; holds source kslot q ^ ((row>>1)&3)
  const int srow  = tid >> 2;
  const int sslot = (((tid & 3) ^ ((tid >> 3) & 3)) << 3);
  const u16* gA = A + (size_t)(bm + srow) * K + sslot;
  const u16* gB = B + (size_t)(bn + srow) * K + sslot;

  auto stageA = [&](int par, int ks, int kt) {
    u16* d = &lds[(par * 2 + ks) * 8192 + wid * 512];
    const u16* s = gA + kt * 64 + ks * 32;
#pragma unroll
    for (int i = 0; i < 2; ++i)
      __builtin_amdgcn_global_load_lds(
          (__attribute__((address_space(1))) const void*)(s + (size_t)i * 128 * K),
          (__attribute__((address_space(3))) void*)(d + i * 4096), 16, 0, 0);
  };
  auto stageB = [&](int par, int ks, int kt) {
    u16* d = &lds[32768 + (par * 2 + ks) * 8192 + wid * 512];
    const u16* s = gB + kt * 64 + ks * 32;
#pragma unroll
    for (int i = 0; i < 2; ++i)
      __builtin_amdgcn_global_load_lds(
          (__attribute__((address_space(1))) const void*)(s + (size_t)i * 128 * K),
          (__attribute__((address_space(3))) void*)(d + i * 4096), 16, 0, 0);
  };

  f32x4 acc[8][4];
#pragma unroll
  for (int i = 0; i < 8; ++i)
#pragma unroll
    for (int n = 0; n < 4; ++n) acc[i][n] = f32x4{0.f, 0.f, 0.f, 0.f};

  const int NT = K >> 6;
  // prologue: stage chunk 0 fully (8 ops in flight)
  stageA(0, 0, 0); stageB(0, 0, 0); stageA(0, 1, 0); stageB(0, 1, 0);

#define GATE4() do { asm volatile("s_waitcnt vmcnt(4)" ::: "memory"); \
                     __builtin_amdgcn_s_barrier(); } while (0)

  for (int t = 0; t < NT; ++t) {
    const int par = t & 1, npar = par ^ 1;
    const int tn = (t + 1 < NT) ? t + 1 : 0;   // wrap keeps vmcnt counting uniform

    auto ldA = [&](int ks, int mf) -> bf16x8 {
      return *(const bf16x8*)&lds[(par * 2 + ks) * 8192 + (wmL + mf * 16 + lr) * 32 + rslot];
    };
    auto ldB = [&](int ks, int nf) -> bf16x8 {
      return *(const bf16x8*)&lds[32768 + (par * 2 + ks) * 8192 + (wnL + nf * 16 + lr) * 32 + rslot];
    };

    bf16x8 a[4], b0[4], b1[4];

    // ---- phase 0: k0 x m0-3 ----  (gate: A[par][0], B[par][0] resident)
    GATE4();
#pragma unroll
    for (int n = 0; n < 4; ++n) b0[n] = ldB(0, n);
#pragma unroll
    for (int i = 0; i < 4; ++i) a[i] = ldA(0, i);
    stageA(npar, 0, tn);
    __builtin_amdgcn_s_setprio(1);
#pragma unroll
    for (int i = 0; i < 4; ++i)
#pragma unroll
      for (int n = 0; n < 4; ++n)
        acc[i][n] = __builtin_amdgcn_mfma_f32_16x16x32_bf16(a[i], b0[n], acc[i][n], 0, 0, 0);
    __builtin_amdgcn_s_setprio(0);

    // ---- phase 1: k0 x m4-7 ----
#pragma unroll
    for (int i = 0; i < 4; ++i) a[i] = ldA(0, 4 + i);
    stageB(npar, 0, tn);
    __builtin_amdgcn_s_setprio(1);
#pragma unroll
    for (int i = 0; i < 4; ++i)
#pragma unroll
      for (int n = 0; n < 4; ++n)
        acc[4 + i][n] = __builtin_amdgcn_mfma_f32_16x16x32_bf16(a[i], b0[n], acc[4 + i][n], 0, 0, 0);
    __builtin_amdgcn_s_setprio(0);

    // ---- phase 2: k1 x m0-3 ----  (gate: A[par][1], B[par][1] resident)
    GATE4();
#pragma unroll
    for (int n = 0; n < 4; ++n) b1[n] = ldB(1, n);
#pragma unroll
    for (int i = 0; i < 4; ++i) a[i] = ldA(1, i);
    stageA(npar, 1, tn);
    __builtin_amdgcn_s_setprio(1);
#pragma unroll
    for (int i = 0; i < 4; ++i)
#pragma unroll
      for (int n = 0; n < 4; ++n)
        acc[i][n] = __builtin_amdgcn_mfma_f32_16x16x32_bf16(a[i], b1[n], acc[i][n], 0, 0, 0);
    __builtin_amdgcn_s_setprio(0);

    // ---- phase 3: k1 x m4-7 ----
#pragma unroll
    for (int i = 0; i < 4; ++i) a[i] = ldA(1, 4 + i);
    stageB(npar, 1, tn);
    __builtin_amdgcn_s_setprio(1);
#pragma unroll
    for (int i = 0; i < 4; ++i)
#pragma unroll
      for (int n = 0; n < 4; ++n)
        acc[4 + i][n] = __builtin_amdgcn_mfma_f32_16x16x32_bf16(a[i], b1[n], acc[4 + i][n], 0, 0, 0);
    __builtin_amdgcn_s_setprio(0);
  }

  // drain trailing (wrapped) staging DMAs before LDS dealloc / kernel end
  asm volatile("s_waitcnt vmcnt(0)" ::: "memory");
  __builtin_amdgcn_s_barrier();

  // epilogue: C/D layout col = lane&15, row = (lane>>4)*4 + j
#pragma unroll
  for (int nf = 0; nf < 4; ++nf) {
    const int col = bn + wnL + nf * 16 + lr;
    const float bv = bias[col];
#pragma unroll
    for (int mf = 0; mf < 8; ++mf) {
      const int row = bm + wmL + mf * 16 + lk * 4;
#pragma unroll
      for (int j = 0; j < 4; ++j)
        C[(size_t)(row + j) * N + col] = acc[mf][nf][j] + bv;
    }
  }
}

extern "C" void kernel_launch(void* const* d_in, const int* in_sizes, int n_in,
                              void* d_out, int out_size, void* d_ws, size_t ws_size,
                              hipStream_t stream) {
  const float* x  = (const float*)d_in[0];
  const float* w  = (const float*)d_in[1];
  const float* lA = (const float*)d_in[2];
  const float* lB = (const float*)d_in[3];
  const float* bs = (const float*)d_in[4];
  float* out = (float*)d_out;

  const int DOUT = in_sizes[4];              // 4096
  const int DIN  = in_sizes[1] / DOUT;       // 4096
  const int M    = in_sizes[0] / DIN;        // 8192

  u16* Xb = (u16*)d_ws;                      // M*DIN bf16
  u16* Wb = Xb + (size_t)M * DIN;            // DOUT*DIN bf16

  const int n4 = (M * DIN) / 4;
  cvt_x_kernel<<<2048, 256, 0, stream>>>((const float4*)x, (u16x4*)Xb, n4);
  weff_kernel<<<DOUT, 256, 0, stream>>>(w, lA, lB, Wb, DIN);

  static bool attr_set = false;
  (void)hipFuncSetAttribute((const void*)gemm256_kernel,
                            hipFuncAttributeMaxDynamicSharedMemorySize, 131072);

  const int nwg = (M / BM) * (DOUT / BN);    // 512
  gemm256_kernel<<<nwg, 512, 131072, stream>>>(Xb, Wb, bs, out, M, DOUT, DIN);
}

// Round 3
// 341.778 us; speedup vs baseline: 1.1778x; 1.0016x over previous
//
#include <hip/hip_runtime.h>
#include <hip/hip_bf16.h>
#include <stdint.h>

typedef unsigned short u16;
typedef u16 u16x4 __attribute__((ext_vector_type(4)));
typedef short bf16x8 __attribute__((ext_vector_type(8)));
typedef float f32x4 __attribute__((ext_vector_type(4)));

__device__ __forceinline__ u16 f2bf(float f) {
  union { float f; uint32_t u; } v; v.f = f;
  uint32_t u = v.u;
  return (u16)((u + 0x7fffu + ((u >> 16) & 1u)) >> 16);
}

// ---------------- fused aux: x fp32->bf16  +  W_eff = W + 2*(B@A) -> bf16 ----------------
__global__ __launch_bounds__(256) void aux_kernel(
    const float4* __restrict__ x, u16x4* __restrict__ xb, int n4, int nCvt,
    const float* __restrict__ W, const float* __restrict__ A,
    const float* __restrict__ Bl, u16* __restrict__ Wout, int DIN) {
  if ((int)blockIdx.x < nCvt) {
    int i = blockIdx.x * 256 + threadIdx.x;
    const int stride = nCvt * 256;
    for (; i < n4; i += stride) {
      float4 v = x[i];
      u16x4 o;
      o.x = f2bf(v.x); o.y = f2bf(v.y); o.z = f2bf(v.z); o.w = f2bf(v.w);
      xb[i] = o;
    }
  } else {
    const int n = blockIdx.x - nCvt;
    float bv[16];
#pragma unroll
    for (int r = 0; r < 16; ++r) bv[r] = 2.0f * Bl[n * 16 + r];
    const int iters = DIN / (256 * 4);
    for (int c = 0; c < iters; ++c) {
      const int k = (c * 256 + (int)threadIdx.x) * 4;
      float4 wv = *(const float4*)&W[(size_t)n * DIN + k];
#pragma unroll
      for (int r = 0; r < 16; ++r) {
        const float4 av = *(const float4*)&A[(size_t)r * DIN + k];
        wv.x += bv[r] * av.x;
        wv.y += bv[r] * av.y;
        wv.z += bv[r] * av.z;
        wv.w += bv[r] * av.w;
      }
      u16x4 o;
      o.x = f2bf(wv.x); o.y = f2bf(wv.y); o.z = f2bf(wv.z); o.w = f2bf(wv.w);
      *(u16x4*)&Wout[(size_t)n * DIN + k] = o;
    }
  }
}

// ---------------- 256x256 deep-pipelined bf16 GEMM, m201-style phase discipline ----------------
// C[M][N] = X[M][K] @ Weff[N][K]^T + bias
// K-chunk = 64 = 2 ksubs of 32. Slab = 256x32 bf16 = 16 KB; A[par][ks], B at +32768 u16.
// Per chunk 4 phases, each: {ds_read ; stage 2 DMA ops ; barrier ; lgkmcnt(0) ;
//   setprio(1) 16 MFMA setprio(0) ; [vmcnt(4) gate at ph1/ph3] ; barrier}.
// Ledger (per wave, steady state): 8 stage-ops outstanding at each gate; vmcnt(4)
// retires exactly the 4 ops whose slabs the next 2 phases read. Writes always cross-parity.
#define BM 256
#define BN 256

__global__ __launch_bounds__(512, 2) void gemm256_kernel(
    const u16* __restrict__ A, const u16* __restrict__ B,
    const float* __restrict__ bias, float* __restrict__ C,
    int M, int N, int K) {
  extern __shared__ u16 lds[];   // 131072 bytes

  const int tid  = threadIdx.x;
  const int lane = tid & 63;
  const int wid  = tid >> 6;

  // XCD-aware block swizzle (nwg % 8 == 0 by launch)
  const int nwg = gridDim.x;
  const int cpx = nwg >> 3;
  const int f   = ((int)blockIdx.x & 7) * cpx + ((int)blockIdx.x >> 3);
  const int nbx = N / BN;
  const int bx = f % nbx, by = f / nbx;
  const int bm = by * BM, bn = bx * BN;

  const int wmL = (wid >> 2) * 128;
  const int wnL = (wid & 3) * 64;
  const int lr  = lane & 15;
  const int lk  = lane >> 4;
  const int rslot = ((lk ^ ((lr >> 1) & 3)) << 3);  // swizzled k-slot (u16 offset)

  // staging: linear LDS dest, pre-swizzled global source (rule #21)
  const int srow  = tid >> 2;
  const int sslot = (((tid & 3) ^ ((tid >> 3) & 3)) << 3);
  const u16* gA = A + (size_t)(bm + srow) * K + sslot;
  const u16* gB = B + (size_t)(bn + srow) * K + sslot;

  auto stageA = [&](int par, int ks, int kt) {
    u16* d = &lds[(par * 2 + ks) * 8192 + wid * 512];
    const u16* s = gA + kt * 64 + ks * 32;
#pragma unroll
    for (int i = 0; i < 2; ++i)
      __builtin_amdgcn_global_load_lds(
          (__attribute__((address_space(1))) const void*)(s + (size_t)i * 128 * K),
          (__attribute__((address_space(3))) void*)(d + i * 4096), 16, 0, 0);
  };
  auto stageB = [&](int par, int ks, int kt) {
    u16* d = &lds[32768 + (par * 2 + ks) * 8192 + wid * 512];
    const u16* s = gB + kt * 64 + ks * 32;
#pragma unroll
    for (int i = 0; i < 2; ++i)
      __builtin_amdgcn_global_load_lds(
          (__attribute__((address_space(1))) const void*)(s + (size_t)i * 128 * K),
          (__attribute__((address_space(3))) void*)(d + i * 4096), 16, 0, 0);
  };

  f32x4 acc[8][4];
#pragma unroll
  for (int i = 0; i < 8; ++i)
#pragma unroll
    for (int n = 0; n < 4; ++n) acc[i][n] = f32x4{0.f, 0.f, 0.f, 0.f};

  const int NT = K >> 6;
  // prologue: stage chunk 0 fully (A00,B00,A01,B01 = 8 ops)
  stageA(0, 0, 0); stageB(0, 0, 0); stageA(0, 1, 0); stageB(0, 1, 0);
  asm volatile("s_waitcnt vmcnt(4)" ::: "memory");   // A00,B00 resident
  __builtin_amdgcn_s_barrier();

#define PIN()   asm volatile("" ::: "memory")
#define LGKM0() asm volatile("s_waitcnt lgkmcnt(0)" ::: "memory")
#define VM4()   asm volatile("s_waitcnt vmcnt(4)" ::: "memory")
#define BAR()   __builtin_amdgcn_s_barrier()

  for (int t = 0; t < NT; ++t) {
    const int par = t & 1, npar = par ^ 1;
    const int tn = (t + 1 < NT) ? t + 1 : 0;   // wrap keeps vmcnt counting uniform

    auto ldA = [&](int ks, int mf) -> bf16x8 {
      return *(const bf16x8*)&lds[(par * 2 + ks) * 8192 + (wmL + mf * 16 + lr) * 32 + rslot];
    };
    auto ldB = [&](int ks, int nf) -> bf16x8 {
      return *(const bf16x8*)&lds[32768 + (par * 2 + ks) * 8192 + (wnL + nf * 16 + lr) * 32 + rslot];
    };

    bf16x8 a[4], b0[4], b1[4];

    // ---- phase 0: ks0 x m0-3 ----
#pragma unroll
    for (int n = 0; n < 4; ++n) b0[n] = ldB(0, n);
#pragma unroll
    for (int i = 0; i < 4; ++i) a[i] = ldA(0, i);
    stageA(npar, 0, tn);
    PIN(); BAR(); LGKM0();
    __builtin_amdgcn_s_setprio(1);
#pragma unroll
    for (int i = 0; i < 4; ++i)
#pragma unroll
      for (int n = 0; n < 4; ++n)
        acc[i][n] = __builtin_amdgcn_mfma_f32_16x16x32_bf16(a[i], b0[n], acc[i][n], 0, 0, 0);
    __builtin_amdgcn_s_setprio(0);
    BAR();

    // ---- phase 1: ks0 x m4-7 ----
#pragma unroll
    for (int i = 0; i < 4; ++i) a[i] = ldA(0, 4 + i);
    stageB(npar, 0, tn);
    PIN(); BAR(); LGKM0();
    __builtin_amdgcn_s_setprio(1);
#pragma unroll
    for (int i = 0; i < 4; ++i)
#pragma unroll
      for (int n = 0; n < 4; ++n)
        acc[4 + i][n] = __builtin_amdgcn_mfma_f32_16x16x32_bf16(a[i], b0[n], acc[4 + i][n], 0, 0, 0);
    __builtin_amdgcn_s_setprio(0);
    VM4();   // gate: A(par,1), B(par,1) resident for phases 2-3
    BAR();

    // ---- phase 2: ks1 x m0-3 ----
#pragma unroll
    for (int n = 0; n < 4; ++n) b1[n] = ldB(1, n);
#pragma unroll
    for (int i = 0; i < 4; ++i) a[i] = ldA(1, i);
    stageA(npar, 1, tn);
    PIN(); BAR(); LGKM0();
    __builtin_amdgcn_s_setprio(1);
#pragma unroll
    for (int i = 0; i < 4; ++i)
#pragma unroll
      for (int n = 0; n < 4; ++n)
        acc[i][n] = __builtin_amdgcn_mfma_f32_16x16x32_bf16(a[i], b1[n], acc[i][n], 0, 0, 0);
    __builtin_amdgcn_s_setprio(0);
    BAR();

    // ---- phase 3: ks1 x m4-7 ----
#pragma unroll
    for (int i = 0; i < 4; ++i) a[i] = ldA(1, 4 + i);
    stageB(npar, 1, tn);
    PIN(); BAR(); LGKM0();
    __builtin_amdgcn_s_setprio(1);
#pragma unroll
    for (int i = 0; i < 4; ++i)
#pragma unroll
      for (int n = 0; n < 4; ++n)
        acc[4 + i][n] = __builtin_amdgcn_mfma_f32_16x16x32_bf16(a[i], b1[n], acc[4 + i][n], 0, 0, 0);
    __builtin_amdgcn_s_setprio(0);
    VM4();   // gate: next chunk's A(npar,0), B(npar,0) resident
    BAR();
  }

  // drain wrapped staging DMAs before LDS dealloc / kernel end
  asm volatile("s_waitcnt vmcnt(0)" ::: "memory");
  __builtin_amdgcn_s_barrier();

  // epilogue: C/D layout col = lane&15, row = (lane>>4)*4 + j
#pragma unroll
  for (int nf = 0; nf < 4; ++nf) {
    const int col = bn + wnL + nf * 16 + lr;
    const float bv = bias[col];
#pragma unroll
    for (int mf = 0; mf < 8; ++mf) {
      const int row = bm + wmL + mf * 16 + lk * 4;
#pragma unroll
      for (int j = 0; j < 4; ++j)
        C[(size_t)(row + j) * N + col] = acc[mf][nf][j] + bv;
    }
  }
#undef PIN
#undef LGKM0
#undef VM4
#undef BAR
}

extern "C" void kernel_launch(void* const* d_in, const int* in_sizes, int n_in,
                              void* d_out, int out_size, void* d_ws, size_t ws_size,
                              hipStream_t stream) {
  const float* x  = (const float*)d_in[0];
  const float* w  = (const float*)d_in[1];
  const float* lA = (const float*)d_in[2];
  const float* lB = (const float*)d_in[3];
  const float* bs = (const float*)d_in[4];
  float* out = (float*)d_out;

  const int DOUT = in_sizes[4];              // 4096
  const int DIN  = in_sizes[1] / DOUT;       // 4096
  const int M    = in_sizes[0] / DIN;        // 8192

  u16* Xb = (u16*)d_ws;                      // M*DIN bf16
  u16* Wb = Xb + (size_t)M * DIN;            // DOUT*DIN bf16

  const int n4 = (M * DIN) / 4;
  const int nCvt = 2048;
  aux_kernel<<<nCvt + DOUT, 256, 0, stream>>>((const float4*)x, (u16x4*)Xb, n4, nCvt,
                                              w, lA, lB, Wb, DIN);

  (void)hipFuncSetAttribute((const void*)gemm256_kernel,
                            hipFuncAttributeMaxDynamicSharedMemorySize, 131072);

  const int nwg = (M / BM) * (DOUT / BN);    // 512
  gemm256_kernel<<<nwg, 512, 131072, stream>>>(Xb, Wb, bs, out, M, DOUT, DIN);
}